// Round 4
// baseline (583.873 us; speedup 1.0000x reference)
//
#include <hip/hip_runtime.h>
#include <hip/hip_bf16.h>

// Problem constants
#define HID    4096
#define NH     32
#define NKVH   8
#define HD     128
#define RLR    64
#define SCACHE 32767
#define STOT   32768
#define GS     4
#define NGRP   8192
#define TOPK   100
#define WIN    4
#define NTOK   404   // TOPK*GS + WIN

// ws layout (float offsets)
#define WS_QKV     0        // 6144: q raw [0,4096) | k raw [4096,5120) | v raw [5120,6144)  (memset 0)
#define WS_QROPE   6144     // 4096
#define WS_KROPE   10240    // 1024
#define WS_QLS     11264    // 512
#define WS_WT      11776    // 8192  Wt[c*8+kvh]
#define WS_ATTN    20480    // 4096
#define WS_SEL     24576    // int: 8*408
#define WS_AGG     32768    // 2*8*32768 = 524288

__device__ __forceinline__ unsigned fkey(float f) {
  unsigned u = __float_as_uint(f);
  return (u & 0x80000000u) ? ~u : (u | 0x80000000u);
}

// ---------------- K1: qkv = hs @ [Wq|Wk|Wv], partial rows, atomicAdd ----------------
__global__ __launch_bounds__(256) void k_qkv(const float* __restrict__ hs,
    const float* __restrict__ Wq, const float* __restrict__ Wk,
    const float* __restrict__ Wv, float* __restrict__ acc_out) {
  int blk = blockIdx.x;
  int colblk = blk % 24;
  int r0 = (blk / 24) * 128;
  const float* W; int col, ncol; float* dst;
  if (colblk < 16)      { W = Wq; ncol = 4096; col = colblk * 256 + threadIdx.x;        dst = acc_out + col; }
  else if (colblk < 20) { W = Wk; ncol = 1024; col = (colblk - 16) * 256 + threadIdx.x; dst = acc_out + 4096 + col; }
  else                  { W = Wv; ncol = 1024; col = (colblk - 20) * 256 + threadIdx.x; dst = acc_out + 5120 + col; }
  const float* wp = W + (size_t)r0 * ncol + col;
  float acc = 0.f;
  #pragma unroll 8
  for (int i = 0; i < 128; ++i)
    acc += hs[r0 + i] * wp[(size_t)i * ncol];
  atomicAdd(dst, acc);
}

// ---------------- K2: RoPE(q,k) + q_lr_sum ----------------
__global__ __launch_bounds__(512) void k_prep(const float* __restrict__ qkv,
    const float* __restrict__ cosv, const float* __restrict__ sinv,
    const float* __restrict__ A, float* __restrict__ q_rope,
    float* __restrict__ k_rope, float* __restrict__ qls) {
  __shared__ float qsum[1024];
  int tid = threadIdx.x;
  #pragma unroll
  for (int e = 0; e < 8; ++e) {
    int idx = e * 512 + tid; int d = idx & 127;
    float x = qkv[idx];
    float other = (d < 64) ? -qkv[idx + 64] : qkv[idx - 64];
    q_rope[idx] = x * cosv[d] + other * sinv[d];
  }
  #pragma unroll
  for (int e = 0; e < 2; ++e) {
    int idx = e * 512 + tid; int d = idx & 127;
    float x = qkv[4096 + idx];
    float other = (d < 64) ? -qkv[4096 + idx + 64] : qkv[4096 + idx - 64];
    k_rope[idx] = x * cosv[d] + other * sinv[d];
  }
  __syncthreads();
  #pragma unroll
  for (int e = 0; e < 2; ++e) {
    int kd = e * 512 + tid; int kvh = kd >> 7; int d = kd & 127;
    const float* qr = q_rope + kvh * 512 + d;
    qsum[kd] = (qr[0] + qr[128]) + (qr[256] + qr[384]);
  }
  __syncthreads();
  int kvh = tid >> 6, r = tid & 63;
  float a = 0.f;
  #pragma unroll 4
  for (int d = 0; d < 128; ++d)
    a += qsum[kvh * 128 + d] * A[(size_t)(kvh * 128 + d) * 64 + r];
  qls[tid] = a;
}

// ---------------- K2b: Wt[c][kvh] = sum_r A[c,r]*qls[kvh,r] ----------------
__global__ __launch_bounds__(256) void k_wt(const float* __restrict__ A,
    const float* __restrict__ qls, float* __restrict__ Wt) {
  __shared__ float qs[512];
  int tid = threadIdx.x;
  qs[tid] = qls[tid]; qs[tid + 256] = qls[tid + 256];
  __syncthreads();
  int c = blockIdx.x * 256 + tid;
  const float* ar = A + (size_t)c * 64;
  float w[8] = {0, 0, 0, 0, 0, 0, 0, 0};
  #pragma unroll 8
  for (int r = 0; r < 64; ++r) {
    float av = ar[r];
    #pragma unroll
    for (int k = 0; k < 8; ++k) w[k] += av * qs[k * 64 + r];
  }
  #pragma unroll
  for (int k = 0; k < 8; ++k) Wt[c * 8 + k] = w[k];
}

// ---------------- K3: agg_part[half][kvh][t] = sum over half of c of k_flat[t,c]*W[kvh,c] ----
// grid 1024 = 512 pos-groups x 2 d-halves; block = 1 wave; lane-per-position.
__global__ __launch_bounds__(64) void k_scores(const float* __restrict__ k_cache,
    const float* __restrict__ k_rope, const float* __restrict__ Wt,
    float* __restrict__ aggp) {
  __shared__ float4 lds4[2048];  // [2][64 pos][16 units]
  const int l = threadIdx.x;
  const int grp = blockIdx.x >> 1;
  const int half = blockIdx.x & 1;
  const int t0 = grp * 64;
  float4 R[16];
  float acc[8] = {0, 0, 0, 0, 0, 0, 0, 0};

  auto load_slice = [&](int s) {
    #pragma unroll
    for (int j = 0; j < 16; ++j) {
      int f = j * 64 + l, pos = f >> 4, u = f & 15;
      int t = t0 + pos;
      const float* row = (t < SCACHE) ? (k_cache + ((size_t)s * SCACHE + t) * 128)
                                      : (k_rope + s * 128);
      R[j] = *(const float4*)(row + half * 64 + u * 4);
    }
  };
  auto write_slice = [&](int b) {
    #pragma unroll
    for (int j = 0; j < 16; ++j) {
      int f = j * 64 + l, pos = f >> 4, u = f & 15;
      int us = (u & 8) | ((u ^ pos) & 7);  // XOR swizzle -> conflict-free ds_read_b128
      lds4[b * 1024 + pos * 16 + us] = R[j];
    }
  };

  load_slice(0);
  #pragma unroll 2
  for (int s = 0; s < 8; ++s) {
    int b = s & 1;
    write_slice(b);
    if (s < 7) load_slice(s + 1);  // prefetch next slice: in flight during compute
    __syncthreads();
    #pragma unroll
    for (int u = 0; u < 16; ++u) {
      int us = (u & 8) | ((u ^ l) & 7);
      float4 kv = lds4[b * 1024 + l * 16 + us];
      const float* wt = Wt + (size_t)(s * 128 + half * 64 + u * 4) * 8;  // uniform -> s_load
      #pragma unroll
      for (int k = 0; k < 8; ++k)
        acc[k] += kv.x * wt[k] + kv.y * wt[8 + k] + kv.z * wt[16 + k] + kv.w * wt[24 + k];
    }
  }
  int t = t0 + l;
  #pragma unroll
  for (int k = 0; k < 8; ++k)
    aggp[half * 262144 + k * 32768 + t] = acc[k];
}

// ---------------- K4: group-max + exact radix-select top-100 + token list ----------------
__global__ __launch_bounds__(256) void k_topk(const float* __restrict__ agg0,
    const float* __restrict__ agg1, int* __restrict__ sel_tok) {
  __shared__ float gm[NGRP];
  __shared__ int hist[256];
  __shared__ int glist[TOPK];
  __shared__ int sh_c1, sh_c2, sh_cgt, sh_kneed;
  __shared__ unsigned sh_prefix;
  int tid = threadIdx.x, kvh = blockIdx.x;
  const float* a0 = agg0 + kvh * 32768;
  const float* a1 = agg1 + kvh * 32768;
  for (int rep = 0; rep < 32; ++rep) {
    int g = rep * 256 + tid;
    float4 x = *(const float4*)(a0 + g * 4);
    float4 y = *(const float4*)(a1 + g * 4);
    float s0 = x.x + y.x, s1 = x.y + y.y, s2 = x.z + y.z, s3 = x.w + y.w;
    gm[g] = fmaxf(fmaxf(s0, s1), fmaxf(s2, s3));
  }
  if (tid == 0) { sh_prefix = 0u; sh_kneed = TOPK; sh_c1 = 0; sh_c2 = 0; sh_cgt = 0; }
  __syncthreads();
  for (int pass = 0; pass < 4; ++pass) {
    int shift = 24 - 8 * pass;
    unsigned maskhi = pass ? (0xFFFFFFFFu << (shift + 8)) : 0u;
    hist[tid] = 0;
    __syncthreads();
    unsigned prefix = sh_prefix;
    for (int rep = 0; rep < 32; ++rep) {
      unsigned key = fkey(gm[rep * 256 + tid]);
      if ((key & maskhi) == prefix)
        atomicAdd(&hist[(key >> shift) & 255], 1);
    }
    __syncthreads();
    if (tid == 0) {
      int kneed = sh_kneed, cum = 0;
      for (int bb = 255; bb >= 0; --bb) {
        int c = hist[bb];
        if (cum + c >= kneed) { sh_prefix = prefix | ((unsigned)bb << shift); sh_kneed = kneed - cum; break; }
        cum += c;
      }
    }
    __syncthreads();
  }
  unsigned tau = sh_prefix;  // exact key of the 100th-largest group max
  int loc = 0;
  for (int rep = 0; rep < 32; ++rep)
    if (fkey(gm[rep * 256 + tid]) > tau) ++loc;
  atomicAdd(&sh_cgt, loc);
  __syncthreads();
  int cgt = sh_cgt;
  for (int rep = 0; rep < 32; ++rep) {
    int g = rep * 256 + tid;
    if (fkey(gm[g]) > tau) { int p = atomicAdd(&sh_c1, 1); glist[p] = g; }
  }
  __syncthreads();
  for (int rep = 0; rep < 32; ++rep) {
    int g = rep * 256 + tid;
    if (fkey(gm[g]) == tau) { int p = atomicAdd(&sh_c2, 1); if (cgt + p < TOPK) glist[cgt + p] = g; }
  }
  __syncthreads();
  if (tid < TOPK) {
    int g = glist[tid];
    #pragma unroll
    for (int j = 0; j < 4; ++j) sel_tok[kvh * 408 + tid * 4 + j] = g * 4 + j;
  }
  if (tid >= TOPK && tid < TOPK + WIN)
    sel_tok[kvh * 408 + 400 + (tid - TOPK)] = (STOT - WIN) + (tid - TOPK);
}

// ---------------- K5: sparse attention per q-head ----------------
__global__ __launch_bounds__(256) void k_attn(const float* __restrict__ k_cache,
    const float* __restrict__ v_cache, const float* __restrict__ k_rope,
    const float* __restrict__ v_new, const float* __restrict__ q_rope,
    const int* __restrict__ sel_tok, float* __restrict__ attn_vec) {
  __shared__ float qv[128];
  __shared__ float pr[NTOK];
  __shared__ int toks[NTOK];
  __shared__ float red[256];
  int tid = threadIdx.x, h = blockIdx.x, kvh = h >> 2;
  if (tid < 128) qv[tid] = q_rope[h * 128 + tid];
  for (int i = tid; i < NTOK; i += 256) toks[i] = sel_tok[kvh * 408 + i];
  __syncthreads();
  float lmax = -3.4e38f;
  for (int i = tid; i < NTOK; i += 256) {
    int t = toks[i];
    const float* kr = (t < SCACHE) ? k_cache + ((size_t)kvh * SCACHE + t) * 128
                                   : k_rope + kvh * 128;
    float dot = 0.f;
    #pragma unroll 8
    for (int d = 0; d < 128; d += 4) {
      float4 kk = *(const float4*)(kr + d);
      dot += qv[d] * kk.x + qv[d + 1] * kk.y + qv[d + 2] * kk.z + qv[d + 3] * kk.w;
    }
    float sc = dot * 0.08838834764831845f;
    pr[i] = sc;
    lmax = fmaxf(lmax, sc);
  }
  red[tid] = lmax; __syncthreads();
  for (int off = 128; off > 0; off >>= 1) {
    if (tid < off) red[tid] = fmaxf(red[tid], red[tid + off]);
    __syncthreads();
  }
  float m = red[0]; __syncthreads();
  float lsum = 0.f;
  for (int i = tid; i < NTOK; i += 256) {
    float e = __expf(pr[i] - m); pr[i] = e; lsum += e;
  }
  red[tid] = lsum; __syncthreads();
  for (int off = 128; off > 0; off >>= 1) {
    if (tid < off) red[tid] += red[tid + off];
    __syncthreads();
  }
  float inv = 1.0f / red[0]; __syncthreads();
  int d = tid & 127, part = tid >> 7;
  float acc = 0.f;
  for (int i = part; i < NTOK; i += 2) {
    int t = toks[i];
    const float* vr = (t < SCACHE) ? v_cache + ((size_t)kvh * SCACHE + t) * 128
                                   : v_new + kvh * 128;
    acc += pr[i] * vr[d];
  }
  red[tid] = acc; __syncthreads();
  if (part == 0) attn_vec[h * 128 + d] = (red[d] + red[d + 128]) * inv;
}

// ---------------- K6: out = attn_vec @ Wo ----------------
__global__ __launch_bounds__(256) void k_out(const float* __restrict__ av,
    const float* __restrict__ Wo, float* __restrict__ out) {
  int blk = blockIdx.x;
  int col = (blk & 15) * 256 + threadIdx.x;
  int r0 = (blk >> 4) * 128;
  const float* wp = Wo + (size_t)r0 * 4096 + col;
  float acc = 0.f;
  #pragma unroll 8
  for (int i = 0; i < 128; ++i)
    acc += av[r0 + i] * wp[(size_t)i * 4096];
  atomicAdd(&out[col], acc);
}

extern "C" void kernel_launch(void* const* d_in, const int* in_sizes, int n_in,
                              void* d_out, int out_size, void* d_ws, size_t ws_size,
                              hipStream_t stream) {
  const float* hs   = (const float*)d_in[0];
  const float* cosv = (const float*)d_in[1];
  const float* sinv = (const float*)d_in[2];
  const float* kc   = (const float*)d_in[3];
  const float* vc   = (const float*)d_in[4];
  const float* Wq   = (const float*)d_in[5];
  const float* Wk   = (const float*)d_in[6];
  const float* Wv   = (const float*)d_in[7];
  const float* Wo   = (const float*)d_in[8];
  const float* A    = (const float*)d_in[9];
  float* ws = (float*)d_ws;
  float* qkv_acc = ws + WS_QKV;
  float* q_rope  = ws + WS_QROPE;
  float* k_rope  = ws + WS_KROPE;
  float* qls     = ws + WS_QLS;
  float* Wt      = ws + WS_WT;
  float* attn_v  = ws + WS_ATTN;
  int*   sel     = (int*)(ws + WS_SEL);
  float* aggp    = ws + WS_AGG;
  float* out = (float*)d_out;

  hipMemsetAsync(qkv_acc, 0, 6144 * sizeof(float), stream);
  hipMemsetAsync(out, 0, 4096 * sizeof(float), stream);

  k_qkv   <<<768, 256, 0, stream>>>(hs, Wq, Wk, Wv, qkv_acc);
  k_prep  <<<1, 512, 0, stream>>>(qkv_acc, cosv, sinv, A, q_rope, k_rope, qls);
  k_wt    <<<4, 256, 0, stream>>>(A, qls, Wt);
  k_scores<<<1024, 64, 0, stream>>>(kc, k_rope, Wt, aggp);
  k_topk  <<<8, 256, 0, stream>>>(aggp, aggp + 262144, sel);
  k_attn  <<<32, 256, 0, stream>>>(kc, vc, k_rope, qkv_acc + 5120, q_rope, sel, attn_v);
  k_out   <<<512, 256, 0, stream>>>(attn_v, Wo, out);
}